// Round 1
// baseline (52.426 us; speedup 1.0000x reference)
//
#include <hip/hip_runtime.h>
#include <hip/hip_bf16.h>

// Problem constants (from reference)
#define BB 4
#define NN 256
#define KK 32
#define DD 32
#define HH 8
#define NSPATIAL 512
#define NEDGE 1025          // NUM_EDGES + 1 rows in edge_feat_emb
#define NPTS (BB * NN * NN) // 262144 output points
#define NNSQ (NN * NN)      // 65536

// ---------------------------------------------------------------------------
// Kernel A: build proj[k][e][h] = sum_d edge_feat_emb[e][d] * W[k][d][h]
// proj is K x NEDGE x H floats = 1,049,600 bytes in d_ws.
// One thread per (k, e) pair -> 32*1025 = 32800 threads.
// ---------------------------------------------------------------------------
__global__ __launch_bounds__(256) void build_proj_kernel(
    const float* __restrict__ feat,   // [NEDGE][DD]
    const float* __restrict__ w,      // [KK][DD*HH]
    float* __restrict__ proj)         // [KK][NEDGE][HH]
{
    int t = blockIdx.x * blockDim.x + threadIdx.x;
    if (t >= KK * NEDGE) return;
    int k = t / NEDGE;
    int e = t - k * NEDGE;

    const float* frow = feat + (size_t)e * DD;
    const float* wrow = w + (size_t)k * DD * HH;

    float acc[HH];
#pragma unroll
    for (int h = 0; h < HH; ++h) acc[h] = 0.0f;

#pragma unroll
    for (int d = 0; d < DD; ++d) {
        float f = frow[d];
#pragma unroll
        for (int h = 0; h < HH; ++h) acc[h] += f * wrow[d * HH + h];
    }

    float4* p = reinterpret_cast<float4*>(proj + (size_t)t * HH);
    p[0] = make_float4(acc[0], acc[1], acc[2], acc[3]);
    p[1] = make_float4(acc[4], acc[5], acc[6], acc[7]);
}

// ---------------------------------------------------------------------------
// Kernel B: main. One thread per (b,n,m) point.
// out[b][h][n][m] = spatial_emb[sp][h] + (sum_k proj[k][e_k][h]) / pathlen
// I64: whether integer inputs arrive as int64 (two ints each, little-endian).
// ---------------------------------------------------------------------------
template <bool I64>
__global__ __launch_bounds__(256) void attn_bias_main_kernel(
    const int* __restrict__ sp,       // [NPTS] (or *2 if I64)
    const int* __restrict__ ei,       // [NPTS*KK] (or *2 if I64)
    const float* __restrict__ semb,   // [NSPATIAL][HH]
    const float* __restrict__ proj,   // [KK][NEDGE][HH]
    float* __restrict__ out)          // [BB][HH][NN][NN]
{
    int idx = blockIdx.x * blockDim.x + threadIdx.x;
    if (idx >= NPTS) return;

    float acc[HH];
#pragma unroll
    for (int h = 0; h < HH; ++h) acc[h] = 0.0f;
    int cnt = 0;

    auto addrow = [&](int k, int e) {
        const float4* p = reinterpret_cast<const float4*>(
            proj + ((size_t)k * NEDGE + e) * HH);
        float4 a = p[0];
        float4 b = p[1];
        acc[0] += a.x; acc[1] += a.y; acc[2] += a.z; acc[3] += a.w;
        acc[4] += b.x; acc[5] += b.y; acc[6] += b.z; acc[7] += b.w;
    };

    if (I64) {
        const int4* e4 = reinterpret_cast<const int4*>(ei + (size_t)idx * KK * 2);
#pragma unroll
        for (int q = 0; q < 16; ++q) {
            int4 v = e4[q];   // two int64 values: (x=lo0,y=hi0,z=lo1,w=hi1)
            int e0 = v.x, e1 = v.z;
            cnt += (e0 != 0) + (e1 != 0);
            addrow(2 * q, e0);
            addrow(2 * q + 1, e1);
        }
    } else {
        const int4* e4 = reinterpret_cast<const int4*>(ei + (size_t)idx * KK);
#pragma unroll
        for (int q = 0; q < 8; ++q) {
            int4 v = e4[q];
            cnt += (v.x != 0) + (v.y != 0) + (v.z != 0) + (v.w != 0);
            addrow(4 * q + 0, v.x);
            addrow(4 * q + 1, v.y);
            addrow(4 * q + 2, v.z);
            addrow(4 * q + 3, v.w);
        }
    }

    float inv = 1.0f / (float)(cnt > 0 ? cnt : 1);

    int s = I64 ? sp[(size_t)idx * 2] : sp[idx];
    const float4* sr = reinterpret_cast<const float4*>(semb + (size_t)s * HH);
    float4 s0 = sr[0];
    float4 s1 = sr[1];
    float sb[HH] = {s0.x, s0.y, s0.z, s0.w, s1.x, s1.y, s1.z, s1.w};

    int b = idx >> 16;          // / NNSQ
    int r = idx & (NNSQ - 1);   // n*NN + m
    float* o = out + (size_t)b * HH * NNSQ + r;
#pragma unroll
    for (int h = 0; h < HH; ++h) {
        o[(size_t)h * NNSQ] = sb[h] + acc[h] * inv;
    }
}

// ---------------------------------------------------------------------------
// Fallback (only if ws_size is too small for proj): direct per-point compute.
// ---------------------------------------------------------------------------
template <bool I64>
__global__ __launch_bounds__(256) void attn_bias_direct_kernel(
    const int* __restrict__ sp,
    const int* __restrict__ ei,
    const float* __restrict__ semb,
    const float* __restrict__ feat,   // [NEDGE][DD]
    const float* __restrict__ w,      // [KK][DD*HH]
    float* __restrict__ out)
{
    __shared__ float wl[KK * DD * HH];  // 32 KiB
    for (int i = threadIdx.x; i < KK * DD * HH; i += blockDim.x) wl[i] = w[i];
    __syncthreads();

    int idx = blockIdx.x * blockDim.x + threadIdx.x;
    if (idx >= NPTS) return;

    float acc[HH];
#pragma unroll
    for (int h = 0; h < HH; ++h) acc[h] = 0.0f;
    int cnt = 0;

    for (int k = 0; k < KK; ++k) {
        int e;
        if (I64) e = ei[((size_t)idx * KK + k) * 2];
        else     e = ei[(size_t)idx * KK + k];
        cnt += (e != 0);
        const float4* f = reinterpret_cast<const float4*>(feat + (size_t)e * DD);
        const float* wk = wl + k * DD * HH;
#pragma unroll
        for (int dq = 0; dq < 8; ++dq) {
            float4 fv = f[dq];
            float fvals[4] = {fv.x, fv.y, fv.z, fv.w};
#pragma unroll
            for (int j = 0; j < 4; ++j) {
                int d = dq * 4 + j;
#pragma unroll
                for (int h = 0; h < HH; ++h) acc[h] += fvals[j] * wk[d * HH + h];
            }
        }
    }

    float inv = 1.0f / (float)(cnt > 0 ? cnt : 1);
    int s = I64 ? sp[(size_t)idx * 2] : sp[idx];
    const float4* sr = reinterpret_cast<const float4*>(semb + (size_t)s * HH);
    float4 s0 = sr[0];
    float4 s1 = sr[1];
    float sb[HH] = {s0.x, s0.y, s0.z, s0.w, s1.x, s1.y, s1.z, s1.w};

    int b = idx >> 16;
    int r = idx & (NNSQ - 1);
    float* o = out + (size_t)b * HH * NNSQ + r;
#pragma unroll
    for (int h = 0; h < HH; ++h) {
        o[(size_t)h * NNSQ] = sb[h] + acc[h] * inv;
    }
}

extern "C" void kernel_launch(void* const* d_in, const int* in_sizes, int n_in,
                              void* d_out, int out_size, void* d_ws, size_t ws_size,
                              hipStream_t stream) {
    const int* sp   = (const int*)d_in[0];    // spatial_pos  [B,N,N]
    const int* ei   = (const int*)d_in[1];    // edge_input   [B,N,N,K]
    const float* se = (const float*)d_in[2];  // spatial_emb  [512,8]
    const float* fe = (const float*)d_in[3];  // edge_feat_emb[1025,32]
    const float* pw = (const float*)d_in[4];  // edge_pos_emb [32,256]
    float* out = (float*)d_out;

    // Detect int64 ABI (indices delivered as raw int64 = 2 ints each).
    const bool i64 = (in_sizes[0] == 2 * NPTS);

    const size_t PROJ_BYTES = (size_t)KK * NEDGE * HH * sizeof(float);
    const int nblocks_main = (NPTS + 255) / 256;

    if (ws_size >= PROJ_BYTES) {
        float* proj = (float*)d_ws;
        const int nblocks_proj = (KK * NEDGE + 255) / 256;
        build_proj_kernel<<<nblocks_proj, 256, 0, stream>>>(fe, pw, proj);
        if (i64) {
            attn_bias_main_kernel<true><<<nblocks_main, 256, 0, stream>>>(
                sp, ei, se, proj, out);
        } else {
            attn_bias_main_kernel<false><<<nblocks_main, 256, 0, stream>>>(
                sp, ei, se, proj, out);
        }
    } else {
        if (i64) {
            attn_bias_direct_kernel<true><<<nblocks_main, 256, 0, stream>>>(
                sp, ei, se, fe, pw, out);
        } else {
            attn_bias_direct_kernel<false><<<nblocks_main, 256, 0, stream>>>(
                sp, ei, se, fe, pw, out);
        }
    }
}